// Round 15
// baseline (150.253 us; speedup 1.0000x reference)
//
#include <hip/hip_runtime.h>

static constexpr float kIouT = 0.35f;
static constexpr float kScoreT = 0.5f;
static constexpr int kMaxKeep = 512;
static constexpr int kNW = 36;   // fast-path word-chunks (m <= 2304; actual ~2048)

// Decision-exact "iou > T" (quick reject; division only for overlapping pairs).
// Validated bit-exact end-to-end (absmax = 0) in rounds 9-13.
__device__ __forceinline__ bool iou_gt(const float4 a, const float4 b) {
  const float iy1 = fmaxf(a.x, b.x), ix1 = fmaxf(a.y, b.y);
  const float iy2 = fminf(a.z, b.z), ix2 = fminf(a.w, b.w);
  const float dy = iy2 - iy1, dx = ix2 - ix1;
  if (!(dy > 0.0f && dx > 0.0f)) return false;
  const float inter = __fmul_rn(dy, dx);
  const float aA = __fmul_rn(a.z - a.x, a.w - a.y);
  const float aB = __fmul_rn(b.z - b.x, b.w - b.y);
  const float uni = (aA + aB) - inter;
  return (uni > 0.0f) && (__fdiv_rn(inter, uni) > kIouT);
}

// 64-bit cross-lane pull with UNIFORM lane index (v_readlane) — fallback only.
__device__ __forceinline__ unsigned long long rdlane64(unsigned long long v,
                                                       int l) {
  unsigned lo = (unsigned)__builtin_amdgcn_readlane((int)(unsigned)v, l);
  unsigned hi = (unsigned)__builtin_amdgcn_readlane((int)(unsigned)(v >> 32), l);
  return ((unsigned long long)hi << 32) | lo;
}

// ------- kernel 1 — rank (counting) sort of the VALID prefix (+count fold) ----
// [round-7 proven form, unchanged]
__global__ __launch_bounds__(256)
void nms_rank_kernel(const float* __restrict__ scores,
                     const float4* __restrict__ boxes,
                     unsigned long long* __restrict__ skeys,
                     float4* __restrict__ sboxes,
                     int* __restrict__ Mcnt, int N, int rankBlocks) {
  const int tid = threadIdx.x;
  const int lane = tid & 63;
  if ((int)blockIdx.x >= rankBlocks) {   // ---- count mode ----
    __shared__ int part[4];
    const int img = blockIdx.x - rankBlocks;
    const int wv = tid >> 6;
    const float4* sc4 = (const float4*)(scores + (size_t)img * N);
    int c = 0;
    for (int q = tid; q < (N >> 2); q += 256) {
      float4 v = sc4[q];
      c += (v.x > kScoreT) + (v.y > kScoreT) + (v.z > kScoreT) + (v.w > kScoreT);
    }
#pragma unroll
    for (int off = 1; off < 64; off <<= 1) c += __shfl_xor(c, off, 64);
    if (lane == 0) part[wv] = c;
    __syncthreads();
    if (tid == 0) Mcnt[img] = part[0] + part[1] + part[2] + part[3];
    return;
  }
  // ---- rank mode ----
  const int wid = (int)(((unsigned)blockIdx.x * blockDim.x + tid) >> 6);
  const int img = wid / N;
  const int row = wid - img * N;
  const float* sc = scores + (size_t)img * N;
  const float si = sc[row];
  if (!(si > kScoreT)) return;
  const float4* sc4 = (const float4*)sc;
  int cnt = 0;
  for (int q = lane; q < (N >> 2); q += 64) {   // coalesced, L1/L2-resident
    const float4 v = sc4[q];
    const int j = q << 2;
    cnt += (v.x > si) + (v.y > si) + (v.z > si) + (v.w > si);
    if (v.x == si && j < row) cnt++;
    if (v.y == si && j + 1 < row) cnt++;
    if (v.z == si && j + 2 < row) cnt++;
    if (v.w == si && j + 3 < row) cnt++;
  }
#pragma unroll
  for (int off = 1; off < 64; off <<= 1) cnt += __shfl_xor(cnt, off, 64);
  if (lane == 0) {
    skeys[(size_t)img * N + cnt] =
        ((unsigned long long)(~__float_as_uint(si)) << 32) | (unsigned)row;
    sboxes[(size_t)img * N + cnt] = boxes[(size_t)img * N + row];
  }
}

// ------- kernel 2 — TRANSPOSED lower-triangle suppression masks --------------
// maskT[w][row] (plane-major): word w of sorted row's mask, bits = candidates
// w*64+lane with (j < row) && iou>T. Same IoU count as the old upper-triangle
// row-major kernel; the transposed layout makes the scan's reads coalesced
// COLUMN loads that are pure functions of the input (prefetchable).
__global__ __launch_bounds__(256)
void nms_maskT_kernel(const float4* __restrict__ sboxes,
                      const int* __restrict__ Mcnt,
                      unsigned long long* __restrict__ maskT,
                      int N, int totalRows) {
  const int wid = (int)(((unsigned)blockIdx.x * blockDim.x + threadIdx.x) >> 6);
  const int lane = threadIdx.x & 63;
  if (wid >= totalRows) return;
  const int img = wid / N;
  const int row = wid - img * N;
  const int m = Mcnt[img];
  if (row >= m) return;
  const float4* sb = sboxes + (size_t)img * N;
  const float4 bi = sb[row];
  const int rc = row >> 6;
  unsigned long long* base = maskT + (size_t)img * (size_t)(N >> 6) * N;
  for (int w = 0; w <= rc; ++w) {
    const int j = (w << 6) | lane;
    const bool sup = (j < row) && iou_gt(bi, sb[j]);
    const unsigned long long bm = __ballot(sup);
    if (lane == 0) base[(size_t)w * N + row] = bm;
  }
}

// ------- kernel 3 — inverted scan: candidate-indexed, zero dependent loads ---
// Per chunk c, registers hold COLUMN c of maskT (slot f = maskT[c][f*64+lane],
// f>=c): slot c = own-row diag word (in-chunk, earlier-candidate bits);
// slots f>c = the w=c term of future chunk f's suppression. Chunk flow:
//   avail from per-lane supfut bit c -> greedy (ctz -> (diagw>>b)&1 ->
//   ballot -> andn2, ~50cy/keep, register-only) -> apply keptbits (uniform
//   SGPR!) to future slots: supfut |= (cur[f] & keptbits) ? bit f : 0.
// Column c+1 prefetched (coalesced) during chunk c. NOTHING on the critical
// path ever waits on a keep-dependent load. Ping-pong via macro (static idx).
#define SCAN_BODY(CVAR, CUR, NXT)                                              \
  {                                                                            \
    const int c_ = (CVAR);                                                     \
    const int cb_ = c_ << 6;                                                   \
    _Pragma("unroll") for (int k = 0; k < kNW; ++k) {                          \
      if (k > c_ && k < nw)                                                    \
        NXT[k] = base[(size_t)(c_ + 1) * N + (k << 6) + lane];                 \
    }                                                                          \
    unsigned long long diagw = 0ull;                                           \
    _Pragma("unroll") for (int k = 0; k < kNW; ++k) {                          \
      if (k == c_) diagw = CUR[k];                                             \
    }                                                                          \
    const bool mysup = ((supfut >> c_) & 1ull) != 0ull;                        \
    unsigned long long avail = ~__ballot(mysup);                               \
    const int rem_ = m - cb_;                                                  \
    if (rem_ < 64) avail &= (1ull << rem_) - 1ull;                             \
    unsigned long long keptbits = 0ull;                                        \
    const int keptbase = kept;                                                 \
    while (avail != 0ull && kept < NS) {                                       \
      const int b = (int)__builtin_ctzll(avail);                               \
      keptbits |= 1ull << b;                                                   \
      kept++;                                                                  \
      const bool sb2 = ((diagw >> b) & 1ull) != 0ull;                          \
      const unsigned long long rc2 = __ballot(sb2);                            \
      avail &= ~rc2;                                                           \
      avail &= ~(1ull << b);                                                   \
    }                                                                          \
    if (lane == 0 && keptbits != 0ull) {                                       \
      unsigned long long kl = keptbits;                                        \
      int kc = keptbase;                                                       \
      while (kl != 0ull) {                                                     \
        const int b = (int)__builtin_ctzll(kl);                                \
        kl &= kl - 1ull;                                                       \
        keptlist[kc++] = cb_ + b;                                              \
      }                                                                        \
    }                                                                          \
    if (keptbits != 0ull) {                                                    \
      _Pragma("unroll") for (int k = 0; k < kNW; ++k) {                        \
        if (k > c_ && k < nw) {                                                \
          if ((CUR[k] & keptbits) != 0ull) supfut |= 1ull << k;                \
        }                                                                      \
      }                                                                        \
    }                                                                          \
  }

__global__ __launch_bounds__(64, 1)
void nms_scanT_kernel(const unsigned long long* __restrict__ skeys,
                      const float4* __restrict__ sboxes,
                      const int* __restrict__ Mcnt,
                      const unsigned long long* __restrict__ maskT,
                      const float* __restrict__ anchors,
                      float* __restrict__ out, int N, int NS) {
  __shared__ int keptlist[kMaxKeep];
  const int img = blockIdx.x;
  const int lane = threadIdx.x;
  int m = Mcnt[img];
  if (m > N) m = N;
  if (m < 0) m = 0;
  const int nw = (m + 63) >> 6;
  const unsigned long long* base =
      maskT + (size_t)img * (size_t)(N >> 6) * N;
  const unsigned long long* kg = skeys + (size_t)img * N;
  const float4* sb = sboxes + (size_t)img * N;
  const float* an = anchors + (size_t)img * (size_t)N * 4;
  float* o = out + (size_t)img * NS * 7;

  int kept = 0;
  if (m > 0 && nw <= kNW) {
    unsigned long long colA[kNW], colB[kNW];
    unsigned long long supfut = 0ull;
#pragma unroll
    for (int k = 0; k < kNW; ++k)
      colA[k] = (k < nw) ? base[(size_t)0 * N + (k << 6) + lane] : 0ull;
    for (int c = 0; c < nw && kept < NS;) {
      SCAN_BODY(c, colA, colB);
      ++c;
      if (c >= nw || kept >= NS) break;
      SCAN_BODY(c, colB, colA);
      ++c;
    }
  } else if (m > 0) {
    // correctness fallback (m > 2304 — unreachable for this input dist):
    // on-the-fly ballots from sboxes; lane l owns remv word l.
    unsigned long long remv = 0ull;
    for (int i = 0; i < m && kept < NS; ++i) {
      const unsigned long long rw = rdlane64(remv, i >> 6);
      if ((rw >> (i & 63)) & 1ull) continue;
      if (lane == 0) keptlist[kept] = i;
      kept++;
      const float4 bi = sb[i];
      for (int w2 = i >> 6; w2 < nw; ++w2) {
        const int j = (w2 << 6) | lane;
        const bool sup = (j > i) && (j < m) && iou_gt(bi, sb[j]);
        const unsigned long long bm = __ballot(sup);
        remv |= (lane == w2) ? bm : 0ull;
      }
    }
  }

  __syncthreads();  // drain keptlist LDS writes
  for (int t = lane; t < kept; t += 64) {
    const int i = keptlist[t];
    const unsigned long long ki = kg[i];
    const float4 bi = sb[i];
    const unsigned idx = (unsigned)ki;
    float* row = o + t * 7;
    row[0] = __uint_as_float(~(unsigned)(ki >> 32));
    row[1] = bi.x; row[2] = bi.y; row[3] = bi.z; row[4] = bi.w;
    row[5] = an[idx * 4 + 2];
    row[6] = an[idx * 4 + 3];
  }
  for (int t = kept * 7 + lane; t < NS * 7; t += 64) o[t] = 0.0f;
}

// --------------- fallback: fused sort + on-the-fly scan (no d_ws) -------------
__global__ __launch_bounds__(1024)
void nms_fused_kernel(const float* __restrict__ scores,
                      const float4* __restrict__ boxes,
                      const float* __restrict__ anchors,
                      float* __restrict__ out, int N, int NS) {
  __shared__ unsigned long long keys[4096];
  __shared__ int s_m;
  if (N > 4096) return;
  const int img = blockIdx.x;
  const int tid = threadIdx.x;
  const float* sc = scores + (size_t)img * N;
  const float4* bx = boxes + (size_t)img * N;
  if (tid == 0) s_m = 0;
  __syncthreads();
  int cnt = 0;
  for (int i = tid; i < N; i += blockDim.x) {
    float s = sc[i];
    keys[i] = ((unsigned long long)(~__float_as_uint(s)) << 32) | (unsigned)i;
    if (s > kScoreT) cnt++;
  }
  if (cnt) atomicAdd(&s_m, cnt);
  __syncthreads();
  for (int k = 2; k <= N; k <<= 1) {
    for (int j = k >> 1; j > 0; j >>= 1) {
      for (int i = tid; i < N; i += blockDim.x) {
        int ixj = i ^ j;
        if (ixj > i) {
          unsigned long long a = keys[i];
          unsigned long long b = keys[ixj];
          bool up = ((i & k) == 0);
          if (up ? (a > b) : (a < b)) { keys[i] = b; keys[ixj] = a; }
        }
      }
      __syncthreads();
    }
  }
  if (tid >= 64) return;
  const int lane = tid;
  const int m = s_m;
  const int nw = (m + 63) >> 6;
  const float* an = anchors + (size_t)img * N * 4;
  float* o = out + (size_t)img * NS * 7;
  unsigned long long remv = 0ull;
  int kept = 0;
  for (int i = 0; i < m && kept < NS; ++i) {
    unsigned long long rw = __shfl(remv, i >> 6, 64);
    if ((rw >> (i & 63)) & 1ull) continue;
    unsigned long long ki = keys[i];
    float4 bi = bx[(unsigned)ki];
    if (lane == 0) {
      unsigned idx = (unsigned)ki;
      float* row = o + kept * 7;
      row[0] = __uint_as_float(~(unsigned)(ki >> 32));
      row[1] = bi.x; row[2] = bi.y; row[3] = bi.z; row[4] = bi.w;
      row[5] = an[idx * 4 + 2];
      row[6] = an[idx * 4 + 3];
    }
    kept++;
    for (int w2 = i >> 6; w2 < nw; ++w2) {
      int j = (w2 << 6) | lane;
      bool sup = false;
      if (j > i && j < m) sup = iou_gt(bi, bx[(unsigned)keys[j]]);
      unsigned long long bm = __ballot(sup);
      if (lane == w2) remv |= bm;
    }
  }
  for (int t = kept * 7 + lane; t < NS * 7; t += 64) o[t] = 0.0f;
}

extern "C" void kernel_launch(void* const* d_in, const int* in_sizes, int n_in,
                              void* d_out, int out_size, void* d_ws, size_t ws_size,
                              hipStream_t stream) {
  const float* scores = (const float*)d_in[0];
  const float4* boxes = (const float4*)d_in[1];
  const float* anchors = (const float*)d_in[2];
  float* out = (float*)d_out;
  const int B = 8;
  const int N = in_sizes[0] / B;      // 4096 boxes/image
  const int NS = out_size / (B * 7);  // 300 samples

  const size_t nTot = (size_t)B * (size_t)N;
  const size_t keysB = nTot * 8;
  const size_t sboxB = nTot * 16;
  const size_t mcntB = 256;
  const size_t maskB = nTot * (size_t)(N >> 6) * 8;
  const size_t need = keysB + sboxB + mcntB + maskB;

  if (ws_size >= need && (N % 256) == 0 && N >= 256 && N <= 4096 &&
      NS <= kMaxKeep) {
    char* p = (char*)d_ws;
    unsigned long long* skeys = (unsigned long long*)p; p += keysB;
    float4* sboxes = (float4*)p;                         p += sboxB;
    int* Mcnt = (int*)p;                                 p += mcntB;
    unsigned long long* maskT = (unsigned long long*)p;

    const int totalRows = B * N;
    const int rankBlocks = totalRows / 4;  // 256 thr = 4 waves per block
    nms_rank_kernel<<<rankBlocks + B, 256, 0, stream>>>(scores, boxes, skeys,
                                                        sboxes, Mcnt, N,
                                                        rankBlocks);
    nms_maskT_kernel<<<rankBlocks, 256, 0, stream>>>(sboxes, Mcnt, maskT, N,
                                                     totalRows);
    nms_scanT_kernel<<<B, 64, 0, stream>>>(skeys, sboxes, Mcnt, maskT, anchors,
                                           out, N, NS);
  } else {
    nms_fused_kernel<<<B, 1024, 0, stream>>>(scores, boxes, anchors, out, N, NS);
  }
}

// Round 16
// 145.215 us; speedup vs baseline: 1.0347x; 1.0347x over previous
//
#include <hip/hip_runtime.h>

static constexpr float kIouT = 0.35f;
static constexpr float kScoreT = 0.5f;
static constexpr int kMaxKeep = 512;

// Bit-exact mirror of the reference IoU (no FMA contraction).
__device__ __forceinline__ float iou_f(const float4 a, const float4 b) {
  float areaA = __fmul_rn(a.z - a.x, a.w - a.y);
  float areaB = __fmul_rn(b.z - b.x, b.w - b.y);
  float iy1 = fmaxf(a.x, b.x);
  float ix1 = fmaxf(a.y, b.y);
  float iy2 = fminf(a.z, b.z);
  float ix2 = fminf(a.w, b.w);
  float dy = fmaxf(iy2 - iy1, 0.0f);
  float dx = fmaxf(ix2 - ix1, 0.0f);
  float inter = __fmul_rn(dy, dx);
  float uni = (areaA + areaB) - inter;
  return (uni > 0.0f) ? __fdiv_rn(inter, uni) : 0.0f;
}

// Decision-exact "iou > T" (fallback kernel only).
__device__ __forceinline__ bool iou_gt(const float4 a, const float4 b) {
  const float iy1 = fmaxf(a.x, b.x), ix1 = fmaxf(a.y, b.y);
  const float iy2 = fminf(a.z, b.z), ix2 = fminf(a.w, b.w);
  const float dy = iy2 - iy1, dx = ix2 - ix1;
  if (!(dy > 0.0f && dx > 0.0f)) return false;
  const float inter = __fmul_rn(dy, dx);
  const float aA = __fmul_rn(a.z - a.x, a.w - a.y);
  const float aB = __fmul_rn(b.z - b.x, b.w - b.y);
  const float uni = (aA + aB) - inter;
  return (uni > 0.0f) && (__fdiv_rn(inter, uni) > kIouT);
}

// 64-bit cross-lane pull with UNIFORM lane index (v_readlane).
__device__ __forceinline__ unsigned long long rdlane64(unsigned long long v,
                                                       int l) {
  unsigned lo = (unsigned)__builtin_amdgcn_readlane((int)(unsigned)v, l);
  unsigned hi = (unsigned)__builtin_amdgcn_readlane((int)(unsigned)(v >> 32), l);
  return ((unsigned long long)hi << 32) | lo;
}

// ------- kernel 1 — rank (counting) sort of the VALID prefix (+count fold) ----
// [round-7 proven form, exact]
__global__ __launch_bounds__(256)
void nms_rank_kernel(const float* __restrict__ scores,
                     const float4* __restrict__ boxes,
                     unsigned long long* __restrict__ skeys,
                     float4* __restrict__ sboxes,
                     int* __restrict__ Mcnt, int N, int rankBlocks) {
  const int tid = threadIdx.x;
  const int lane = tid & 63;
  if ((int)blockIdx.x >= rankBlocks) {   // ---- count mode ----
    __shared__ int part[4];
    const int img = blockIdx.x - rankBlocks;
    const int wv = tid >> 6;
    const float4* sc4 = (const float4*)(scores + (size_t)img * N);
    int c = 0;
    for (int q = tid; q < (N >> 2); q += 256) {
      float4 v = sc4[q];
      c += (v.x > kScoreT) + (v.y > kScoreT) + (v.z > kScoreT) + (v.w > kScoreT);
    }
#pragma unroll
    for (int off = 1; off < 64; off <<= 1) c += __shfl_xor(c, off, 64);
    if (lane == 0) part[wv] = c;
    __syncthreads();
    if (tid == 0) Mcnt[img] = part[0] + part[1] + part[2] + part[3];
    return;
  }
  // ---- rank mode ----
  const int wid = (int)(((unsigned)blockIdx.x * blockDim.x + tid) >> 6);
  const int img = wid / N;
  const int row = wid - img * N;
  const float* sc = scores + (size_t)img * N;
  const float si = sc[row];
  if (!(si > kScoreT)) return;
  const float4* sc4 = (const float4*)sc;
  int cnt = 0;
  for (int q = lane; q < (N >> 2); q += 64) {   // coalesced, L1/L2-resident
    const float4 v = sc4[q];
    const int j = q << 2;
    cnt += (v.x > si) + (v.y > si) + (v.z > si) + (v.w > si);
    if (v.x == si && j < row) cnt++;
    if (v.y == si && j + 1 < row) cnt++;
    if (v.z == si && j + 2 < row) cnt++;
    if (v.w == si && j + 3 < row) cnt++;
  }
#pragma unroll
  for (int off = 1; off < 64; off <<= 1) cnt += __shfl_xor(cnt, off, 64);
  if (lane == 0) {
    skeys[(size_t)img * N + cnt] =
        ((unsigned long long)(~__float_as_uint(si)) << 32) | (unsigned)row;
    sboxes[(size_t)img * N + cnt] = boxes[(size_t)img * N + row];
  }
}

// ------------- kernel 2 — pairwise IoU suppression masks [round-7 exact] -----
__global__ __launch_bounds__(256)
void nms_mask_kernel(const float4* __restrict__ sboxes,
                     const int* __restrict__ Mcnt,
                     unsigned long long* __restrict__ mask,
                     int N, int totalRows) {
  const int wid = (int)(((unsigned)blockIdx.x * blockDim.x + threadIdx.x) >> 6);
  const int lane = threadIdx.x & 63;
  if (wid >= totalRows) return;
  const int img = wid / N;
  const int row = wid - img * N;
  const int m = Mcnt[img];
  if (row >= m) return;
  const float4* sb = sboxes + (size_t)img * N;
  const float4 bi = sb[row];
  const int nw = (m + 63) >> 6;
  unsigned long long* mrow = mask + (size_t)wid * (size_t)(N >> 6);
  for (int w = row >> 6; w < nw; ++w) {
    int j = (w << 6) | lane;
    bool sup = false;
    if (j > row && j < m) sup = iou_f(bi, sb[j]) > kIouT;
    unsigned long long bm = __ballot(sup);
    if (lane == 0) mrow[w] = bm;
  }
}

// ------- kernel 3 — round-7 scan (wave 0, bit-identical) + 7 WARMING waves ---
// Waves 1..7 asynchronously sweep the image's mask rows (consumer order) with
// sunk reads — pulling dirty remote-L2 lines into the LOCAL XCD L2 while the
// consumer runs. NO synchronization with the consumer (round 8's barrier
// coupling was the failure mode); the consumer's dependent 16-deep batches
// progressively become local-L2 hits. Consumer wave raised to priority 1.
__global__ __launch_bounds__(512, 1)
void nms_scan_kernel(const unsigned long long* __restrict__ skeys,
                     const float4* __restrict__ sboxes,
                     const int* __restrict__ Mcnt,
                     const unsigned long long* __restrict__ mask,
                     const float* __restrict__ anchors,
                     float* __restrict__ out, int N, int NS) {
  __shared__ int keptlist[kMaxKeep];
  __shared__ int s_kept;
  const int img = blockIdx.x;
  const int tid = threadIdx.x;
  const int lane = tid & 63;
  const int wv = tid >> 6;
  int m = Mcnt[img];
  if (m > N) m = N;
  if (m < 0) m = 0;
  const int nw = (m + 63) >> 6;        // <= 64 since m <= 4096
  const int stride = N >> 6;
  const unsigned long long* mbase = mask + (size_t)img * (size_t)N * stride;
  const unsigned long long* kg = skeys + (size_t)img * N;
  const float4* sb = sboxes + (size_t)img * N;
  const float* an = anchors + (size_t)img * (size_t)N * 4;
  float* o = out + (size_t)img * NS * 7;

  if (wv == 0) {
    // ================== consumer: round-7 body, bit-identical ==============
    __builtin_amdgcn_s_setprio(1);
    int kept = 0;
    unsigned long long remv = 0ull;
    if (m > 0) {
      auto dgload = [&](int cc) -> unsigned long long {
        const int cl = cc < (nw - 1) ? cc : (nw - 1);
        return mbase[(size_t)((cl << 6) + lane) * stride + cl];
      };
      unsigned long long dg0 = dgload(0);
      unsigned long long dg1 = dgload(1);
      unsigned long long dg2 = dgload(2);

      for (int c = 0; c < nw && kept < NS; ++c) {
        const int cb = c << 6;
        unsigned long long local = rdlane64(remv, c);
        const int rem = m - cb;
        unsigned long long avail = ~local;
        if (rem < 64) avail &= (1ull << rem) - 1ull;
        unsigned long long keptbits = 0ull;
        const int keptbase = kept;
        // ---- serial greedy loop: pure scalar + readlane ----
        while (avail != 0ull && kept < NS) {
          const int b = (int)__builtin_ctzll(avail);
          keptbits |= 1ull << b;
          kept++;
          const unsigned long long rc = rdlane64(dg0, b);
          local |= rc;
          avail &= ~local;
          avail &= ~(1ull << b);
        }
        dg0 = dg1; dg1 = dg2; dg2 = dgload(c + 3);
        if (keptbits != 0ull) {
          if (lane == 0) {
            unsigned long long kl = keptbits;
            int kc = keptbase;
            while (kl != 0ull) {
              const int b = (int)__builtin_ctzll(kl);
              kl &= kl - 1ull;
              keptlist[kc++] = cb + b;
            }
          }
          if (kept < NS || c + 1 < nw) {
            const bool lok = (lane > c) && (lane < nw);
            unsigned long long kb = keptbits;
            while (kb != 0ull) {
              int bs[16];
              int bcur = (int)__builtin_ctzll(kb);
#pragma unroll
              for (int k = 0; k < 16; ++k) {
                if (kb != 0ull) {
                  bcur = (int)__builtin_ctzll(kb);
                  kb &= kb - 1ull;
                }
                bs[k] = bcur;
              }
              unsigned long long t[16];
#pragma unroll
              for (int k = 0; k < 16; ++k)
                t[k] = mbase[(size_t)(cb + bs[k]) * stride + lane];
              unsigned long long acc = 0ull;
#pragma unroll
              for (int k = 0; k < 16; ++k) acc |= t[k];
              if (lok) remv |= acc;
            }
          }
        }
      }
    }
    if (lane == 0) s_kept = kept;
    __builtin_amdgcn_s_setprio(0);
  } else {
    // ================== warming waves: async L2 pull, no sync ==============
    // Wave w covers rows (w-1), (w-1)+7, ... in consumer order; lane = word.
    // acc sink via asm keeps the loads alive (rule #17).
    unsigned long long a0 = 0ull, a1 = 0ull, a2 = 0ull, a3 = 0ull;
    const int r0 = wv - 1;
    for (int r = r0; r < m; r += 28) {           // 4-way independent streams
      const int ra = r, rb = r + 7, rc2 = r + 14, rd = r + 21;
      if (lane < nw) {
        if (ra < m && lane >= (ra >> 6))
          a0 |= mbase[(size_t)ra * stride + lane];
        if (rb < m && lane >= (rb >> 6))
          a1 |= mbase[(size_t)rb * stride + lane];
        if (rc2 < m && lane >= (rc2 >> 6))
          a2 |= mbase[(size_t)rc2 * stride + lane];
        if (rd < m && lane >= (rd >> 6))
          a3 |= mbase[(size_t)rd * stride + lane];
      }
    }
    a0 |= a1 | a2 | a3;
    asm volatile("" ::"v"(a0));
  }

  __syncthreads();
  const int K = s_kept;
  // parallel output: 512 threads over K kept rows
  for (int t = tid; t < K; t += 512) {
    const int i = keptlist[t];
    const unsigned long long ki = kg[i];
    const float4 bi = sb[i];
    const unsigned idx = (unsigned)ki;
    float* row = o + t * 7;
    row[0] = __uint_as_float(~(unsigned)(ki >> 32));
    row[1] = bi.x; row[2] = bi.y; row[3] = bi.z; row[4] = bi.w;
    row[5] = an[idx * 4 + 2];
    row[6] = an[idx * 4 + 3];
  }
  for (int t = K * 7 + tid; t < NS * 7; t += 512) o[t] = 0.0f;
}

// --------------- fallback: fused sort + on-the-fly scan (no d_ws) -------------
__global__ __launch_bounds__(1024)
void nms_fused_kernel(const float* __restrict__ scores,
                      const float4* __restrict__ boxes,
                      const float* __restrict__ anchors,
                      float* __restrict__ out, int N, int NS) {
  __shared__ unsigned long long keys[4096];
  __shared__ int s_m;
  if (N > 4096) return;
  const int img = blockIdx.x;
  const int tid = threadIdx.x;
  const float* sc = scores + (size_t)img * N;
  const float4* bx = boxes + (size_t)img * N;
  if (tid == 0) s_m = 0;
  __syncthreads();
  int cnt = 0;
  for (int i = tid; i < N; i += blockDim.x) {
    float s = sc[i];
    keys[i] = ((unsigned long long)(~__float_as_uint(s)) << 32) | (unsigned)i;
    if (s > kScoreT) cnt++;
  }
  if (cnt) atomicAdd(&s_m, cnt);
  __syncthreads();
  for (int k = 2; k <= N; k <<= 1) {
    for (int j = k >> 1; j > 0; j >>= 1) {
      for (int i = tid; i < N; i += blockDim.x) {
        int ixj = i ^ j;
        if (ixj > i) {
          unsigned long long a = keys[i];
          unsigned long long b = keys[ixj];
          bool up = ((i & k) == 0);
          if (up ? (a > b) : (a < b)) { keys[i] = b; keys[ixj] = a; }
        }
      }
      __syncthreads();
    }
  }
  if (tid >= 64) return;
  const int lane = tid;
  const int m = s_m;
  const int nw = (m + 63) >> 6;
  const float* an = anchors + (size_t)img * N * 4;
  float* o = out + (size_t)img * NS * 7;
  unsigned long long remv = 0ull;
  int kept = 0;
  for (int i = 0; i < m && kept < NS; ++i) {
    unsigned long long rw = __shfl(remv, i >> 6, 64);
    if ((rw >> (i & 63)) & 1ull) continue;
    unsigned long long ki = keys[i];
    float4 bi = bx[(unsigned)ki];
    if (lane == 0) {
      unsigned idx = (unsigned)ki;
      float* row = o + kept * 7;
      row[0] = __uint_as_float(~(unsigned)(ki >> 32));
      row[1] = bi.x; row[2] = bi.y; row[3] = bi.z; row[4] = bi.w;
      row[5] = an[idx * 4 + 2];
      row[6] = an[idx * 4 + 3];
    }
    kept++;
    for (int w2 = i >> 6; w2 < nw; ++w2) {
      int j = (w2 << 6) | lane;
      bool sup = false;
      if (j > i && j < m) sup = iou_gt(bi, bx[(unsigned)keys[j]]);
      unsigned long long bm = __ballot(sup);
      if (lane == w2) remv |= bm;
    }
  }
  for (int t = kept * 7 + lane; t < NS * 7; t += 64) o[t] = 0.0f;
}

extern "C" void kernel_launch(void* const* d_in, const int* in_sizes, int n_in,
                              void* d_out, int out_size, void* d_ws, size_t ws_size,
                              hipStream_t stream) {
  const float* scores = (const float*)d_in[0];
  const float4* boxes = (const float4*)d_in[1];
  const float* anchors = (const float*)d_in[2];
  float* out = (float*)d_out;
  const int B = 8;
  const int N = in_sizes[0] / B;      // 4096 boxes/image
  const int NS = out_size / (B * 7);  // 300 samples

  const size_t nTot = (size_t)B * (size_t)N;
  const size_t keysB = nTot * 8;
  const size_t sboxB = nTot * 16;
  const size_t mcntB = 256;
  const size_t maskB = nTot * (size_t)(N >> 6) * 8;
  const size_t need = keysB + sboxB + mcntB + maskB;

  if (ws_size >= need && (N % 256) == 0 && N >= 256 && N <= 4096 &&
      NS <= kMaxKeep) {
    char* p = (char*)d_ws;
    unsigned long long* skeys = (unsigned long long*)p; p += keysB;
    float4* sboxes = (float4*)p;                         p += sboxB;
    int* Mcnt = (int*)p;                                 p += mcntB;
    unsigned long long* mask = (unsigned long long*)p;

    const int totalRows = B * N;
    const int rankBlocks = totalRows / 4;  // 256 thr = 4 waves per block
    nms_rank_kernel<<<rankBlocks + B, 256, 0, stream>>>(scores, boxes, skeys,
                                                        sboxes, Mcnt, N,
                                                        rankBlocks);
    nms_mask_kernel<<<rankBlocks, 256, 0, stream>>>(sboxes, Mcnt, mask, N,
                                                    totalRows);
    nms_scan_kernel<<<B, 512, 0, stream>>>(skeys, sboxes, Mcnt, mask, anchors,
                                           out, N, NS);
  } else {
    nms_fused_kernel<<<B, 1024, 0, stream>>>(scores, boxes, anchors, out, N, NS);
  }
}